// Round 10
// baseline (1511.910 us; speedup 1.0000x reference)
//
#include <hip/hip_runtime.h>
#include <hip/hip_bf16.h>

// APPNP: z = MLP(x) (bf16 MFMA, pre-packed weights); then 10x propagation
// x_{k+1} = 0.9 * A_hat x_k + 0.1 * z.
// Propagation state g = dinv*x_k is split into TWO feature-half buffers
// (n x 32 bf16, 64 B rows, 6.4 MB each). Persistent blocks read their XCD id
// (s_getreg HW_REG_XCC_ID) and prefer the half matching their XCD parity via
// per-half atomic work queues -> gathers mostly hit the local 4 MB L2.
// CSR built via contention-free two-pass bucket partition (packed int pairs).

#define HIDDEN 256
#define OUTF   64
#define NB_BLK 256

typedef __attribute__((ext_vector_type(8))) unsigned short ushort8;
typedef __attribute__((ext_vector_type(8))) short short8v;
typedef __attribute__((ext_vector_type(4))) float f32x4;

__device__ inline float b2f(unsigned short u) {
    union { unsigned int i; float f; } c;
    c.i = ((unsigned int)u) << 16;
    return c.f;
}
__device__ inline unsigned short f2b(float f) {
    union { float f; unsigned int i; } c;
    c.f = f;
    unsigned int x = c.i;
    unsigned int r = (x + 0x7fff + ((x >> 16) & 1)) >> 16;  // RNE
    return (unsigned short)r;
}
__device__ inline short8v cvt8v(float4 A, float4 B) {
    short8v o;
    o[0] = (short)f2b(A.x); o[1] = (short)f2b(A.y);
    o[2] = (short)f2b(A.z); o[3] = (short)f2b(A.w);
    o[4] = (short)f2b(B.x); o[5] = (short)f2b(B.y);
    o[6] = (short)f2b(B.z); o[7] = (short)f2b(B.w);
    return o;
}
__device__ inline short8v cvt8(const float* s) {
    return cvt8v(((const float4*)s)[0], ((const float4*)s)[1]);
}

// ---------- int64/int32 edge-index hedge ----------
__device__ inline bool detect_i64(const int* __restrict__ p) {
    int acc = 0;
#pragma unroll
    for (int i = 0; i < 16; ++i) acc |= p[2 * i + 1];
    return acc == 0;
}
__device__ inline int load_idx(const void* eiv, long long flat, bool is64) {
    if (is64) return (int)((const long long*)eiv)[flat];
    return ((const int*)eiv)[flat];
}

// ---------- P0: per-block bucket histogram ----------
__global__ __launch_bounds__(256) void part_hist_kernel(const void* __restrict__ eiv,
                                                        long long E, int* __restrict__ bh,
                                                        int n, int nb) {
    __shared__ int hist[512];
    bool is64 = detect_i64((const int*)eiv);
    int t = threadIdx.x, b = blockIdx.x;
    for (int i = t; i < 512; i += 256) hist[i] = 0;
    __syncthreads();
    long long chunk = (E + NB_BLK - 1) / NB_BLK;
    long long beg = (long long)b * chunk, end = min(E, beg + chunk);
    for (long long e = beg + t; e < end; e += 256) {
        int c = load_idx(eiv, E + e, is64);
        if ((unsigned)c < (unsigned)n) atomicAdd(&hist[c >> 8], 1);
    }
    __syncthreads();
    for (int i = t; i < nb; i += 256) bh[i * NB_BLK + b] = hist[i];
}

// ---------- P1a: per-bucket scan over blocks ----------
__global__ __launch_bounds__(256) void part_colscan_kernel(const int* __restrict__ bh,
                                                           int* __restrict__ pre,
                                                           int* __restrict__ btot) {
    __shared__ int s[NB_BLK];
    int g = blockIdx.x, t = threadIdx.x;
    int v = bh[g * NB_BLK + t];
    s[t] = v;
    __syncthreads();
    for (int o = 1; o < NB_BLK; o <<= 1) {
        int tv = (t >= o) ? s[t - o] : 0;
        __syncthreads();
        s[t] += tv;
        __syncthreads();
    }
    pre[g * NB_BLK + t] = s[t] - v;
    if (t == NB_BLK - 1) btot[g] = s[t];
}

// ---------- P1b: scan over buckets ----------
__global__ __launch_bounds__(512) void part_bscan_kernel(const int* __restrict__ btot,
                                                         int* __restrict__ bofs, int nb) {
    __shared__ int s[512];
    int t = threadIdx.x;
    int v = (t < nb) ? btot[t] : 0;
    s[t] = v;
    __syncthreads();
    for (int o = 1; o < 512; o <<= 1) {
        int tv = (t >= o) ? s[t - o] : 0;
        __syncthreads();
        s[t] += tv;
        __syncthreads();
    }
    if (t < nb) bofs[t] = s[t] - v;
    if (t == 511) bofs[nb] = s[511];
}

// ---------- P2: stable scatter of packed pairs ((c&255)<<24 | r) ----------
__global__ __launch_bounds__(256) void part_scatter_kernel(const void* __restrict__ eiv,
                                                           long long E,
                                                           const int* __restrict__ bofs,
                                                           const int* __restrict__ pre,
                                                           unsigned int* __restrict__ pairs,
                                                           int n, int nb) {
    __shared__ int cur[512];
    bool is64 = detect_i64((const int*)eiv);
    int t = threadIdx.x, b = blockIdx.x;
    for (int i = t; i < nb; i += 256) cur[i] = bofs[i] + pre[i * NB_BLK + b];
    __syncthreads();
    long long chunk = (E + NB_BLK - 1) / NB_BLK;
    long long beg = (long long)b * chunk, end = min(E, beg + chunk);
    for (long long e = beg + t; e < end; e += 256) {
        int r = load_idx(eiv, e, is64);
        int c = load_idx(eiv, E + e, is64);
        if ((unsigned)c >= (unsigned)n || (unsigned)r >= (unsigned)n) continue;
        int pos = atomicAdd(&cur[c >> 8], 1);
        pairs[pos] = ((unsigned int)(c & 255) << 24) | (unsigned int)r;
    }
}

// ---------- P3: per-bucket CSR build + dinv ----------
__global__ __launch_bounds__(256) void csr_bucket_kernel(const unsigned int* __restrict__ pairs,
                                                         const int* __restrict__ bofs,
                                                         int* __restrict__ ofs,
                                                         float* __restrict__ dinv,
                                                         int* __restrict__ csr_src,
                                                         int n, int nb) {
    __shared__ int hist[256];
    __shared__ int scn[256];
    int b = blockIdx.x;
    int t = threadIdx.x;
    int node0 = b << 8;
    int cnt = min(256, n - node0);

    hist[t] = 0;
    __syncthreads();
    int beg = bofs[b], end = bofs[b + 1];
    for (int e = beg + t; e < end; e += 256) atomicAdd(&hist[pairs[e] >> 24], 1);
    __syncthreads();
    int v = hist[t];
    scn[t] = v;
    __syncthreads();
    for (int o = 1; o < 256; o <<= 1) {
        int tv = (t >= o) ? scn[t - o] : 0;
        __syncthreads();
        scn[t] += tv;
        __syncthreads();
    }
    int excl = scn[t] - v;
    if (t < cnt) {
        ofs[node0 + t] = beg + excl;
        dinv[node0 + t] = rsqrtf((float)(v + 1));
    }
    if (b == nb - 1 && t == 0) ofs[n] = end;
    __syncthreads();
    hist[t] = beg + excl;
    __syncthreads();
    for (int e = beg + t; e < end; e += 256) {
        unsigned int pr = pairs[e];
        int pos = atomicAdd(&hist[pr >> 24], 1);
        csr_src[pos] = (int)(pr & 0xFFFFFFu);
    }
}

// ---------- pack w1/w2 into bf16 fragment-linear layouts ----------
__global__ __launch_bounds__(256) void pack_w_kernel(const float* __restrict__ w1,
                                                     const float* __restrict__ w2,
                                                     unsigned short* __restrict__ w1p,
                                                     unsigned short* __restrict__ w2p) {
    int id = blockIdx.x * 256 + threadIdx.x;
    if (id < 8192) {
        int ks = id >> 10, rem = id & 1023;
        int f = rem >> 2, kg = rem & 3;
        short8v o = cvt8(w1 + (size_t)f * HIDDEN + ks * 32 + kg * 8);
        *(short8v*)(w1p + ((size_t)(ks * 1024 + (f >> 4) * 64 + kg * 16 + (f & 15)) << 3)) = o;
    } else if (id < 8192 + 2048) {
        int q = id - 8192;
        int j = q >> 5, kslot = q & 31;
        short8v o = cvt8(w2 + (size_t)j * HIDDEN + kslot * 8);
        *(short8v*)(w2p +
                    ((size_t)((j >> 4) * 512 + (kslot >> 2) * 64 + (kslot & 3) * 16 + (j & 15))
                     << 3)) = o;
    }
}

// ---------- fused MFMA MLP, 8 waves, 2-deep x prefetch ----------
// Epilogue writes half-split xb = bf16(0.1*z) and g0 = bf16(dinv*z).
__global__ __launch_bounds__(512) void mlp_mfma_kernel(const float* __restrict__ x,
                                                       const unsigned short* __restrict__ w1p,
                                                       const float* __restrict__ b1,
                                                       const unsigned short* __restrict__ w2p,
                                                       const float* __restrict__ b2,
                                                       const float* __restrict__ dinv,
                                                       unsigned short* __restrict__ xbh0,
                                                       unsigned short* __restrict__ xbh1,
                                                       unsigned short* __restrict__ g00,
                                                       unsigned short* __restrict__ g01, int n) {
    __shared__ __align__(16) union {
        struct { unsigned short w1s[8192]; unsigned short xs[2048]; } p1;  // 20 KB
        unsigned short h[64 * 264];                                        // 33 KB
    } u;

    const int t = threadIdx.x;   // 0..511
    const int w = t >> 6;        // wave 0..7
    const int l = t & 63;
    const int c = l & 15, g = l >> 4;
    const int node0 = blockIdx.x * 64;

    const bool xrole = (t < 256);
    const int sm = t >> 2, skg = t & 3;
    const int snode = node0 + sm;
    const int wu0 = t - 256;
    const int xunit = ((sm >> 4) * 64 + skg * 16 + (sm & 15)) << 3;

    f32x4 acc[4][2];
#pragma unroll
    for (int a = 0; a < 4; ++a)
#pragma unroll
        for (int b = 0; b < 2; ++b) acc[a][b] = (f32x4)0.f;

    float4 pxa0 = make_float4(0.f, 0.f, 0.f, 0.f), pxb0 = pxa0;
    float4 pxa1 = pxa0, pxb1 = pxa0;
    short8v pw[4];

    auto loadx = [&](int ks, float4& A, float4& B) {
        if (snode < n) {
            const float4* xp = (const float4*)(x + (size_t)snode * HIDDEN + ks * 32 + skg * 8);
            A = xp[0];
            B = xp[1];
        }
    };
    auto loadw = [&](int ks) {
        const unsigned short* wsrc = w1p + (size_t)ks * 8192;
#pragma unroll
        for (int i = 0; i < 4; ++i)
            pw[i] = *(const short8v*)(wsrc + ((size_t)(wu0 + i * 256) << 3));
    };
    auto mfma_step = [&]() {
        short8v af[4], bf[2];
#pragma unroll
        for (int mt = 0; mt < 4; ++mt)
            af[mt] = *(const short8v*)&u.p1.xs[(mt * 64 + l) << 3];
#pragma unroll
        for (int j = 0; j < 2; ++j)
            bf[j] = *(const short8v*)&u.p1.w1s[((w * 2 + j) * 64 + l) << 3];
#pragma unroll
        for (int mt = 0; mt < 4; ++mt)
#pragma unroll
            for (int j = 0; j < 2; ++j)
                acc[mt][j] =
                    __builtin_amdgcn_mfma_f32_16x16x32_bf16(af[mt], bf[j], acc[mt][j], 0, 0, 0);
    };
    auto wwrite = [&]() {
#pragma unroll
        for (int i = 0; i < 4; ++i)
            *(short8v*)&u.p1.w1s[(wu0 + i * 256) << 3] = pw[i];
    };

    if (xrole) {
        loadx(0, pxa0, pxb0);
        loadx(1, pxa1, pxb1);
    } else {
        loadw(0);
    }

    for (int ks = 0; ks < 8; ks += 2) {
        if (xrole) *(short8v*)&u.p1.xs[xunit] = cvt8v(pxa0, pxb0);
        else wwrite();
        __syncthreads();
        if (xrole) {
            if (ks + 2 < 8) loadx(ks + 2, pxa0, pxb0);
        } else {
            loadw(ks + 1);
        }
        mfma_step();
        __syncthreads();
        if (xrole) *(short8v*)&u.p1.xs[xunit] = cvt8v(pxa1, pxb1);
        else wwrite();
        __syncthreads();
        if (xrole) {
            if (ks + 3 < 8) loadx(ks + 3, pxa1, pxb1);
        } else {
            if (ks + 2 < 8) loadw(ks + 2);
        }
        mfma_step();
        __syncthreads();
    }

#pragma unroll
    for (int j = 0; j < 2; ++j) {
        int col = w * 32 + j * 16 + c;
        float b1v = b1[col];
#pragma unroll
        for (int mt = 0; mt < 4; ++mt)
#pragma unroll
            for (int r = 0; r < 4; ++r) {
                int row = mt * 16 + g * 4 + r;
                u.h[row * 264 + col] = f2b(fmaxf(acc[mt][j][r] + b1v, 0.f));
            }
    }
    __syncthreads();

    const int rt = w >> 1;
    const int cb = (w & 1) * 2;
    f32x4 acc2[2];
#pragma unroll
    for (int j = 0; j < 2; ++j) acc2[j] = (f32x4)0.f;
#pragma unroll
    for (int ks = 0; ks < 8; ++ks) {
        short8v a2 = *(const short8v*)&u.h[(rt * 16 + c) * 264 + ks * 32 + g * 8];
#pragma unroll
        for (int j = 0; j < 2; ++j) {
            short8v bv = *(const short8v*)(w2p + ((size_t)((cb + j) * 512 + ks * 64 + l) << 3));
            acc2[j] = __builtin_amdgcn_mfma_f32_16x16x32_bf16(a2, bv, acc2[j], 0, 0, 0);
        }
    }
#pragma unroll
    for (int j = 0; j < 2; ++j) {
        int col = (cb + j) * 16 + c;
        int h2 = col >> 5;
        int col32 = col & 31;
        float bb = b2[col];
        unsigned short* xbp = h2 ? xbh1 : xbh0;
        unsigned short* gp = h2 ? g01 : g00;
#pragma unroll
        for (int r = 0; r < 4; ++r) {
            int node = node0 + rt * 16 + g * 4 + r;
            if (node < n) {
                float zv = acc2[j][r] + bb;
                float di = dinv[node];
                size_t idx = ((size_t)node << 5) + col32;
                xbp[idx] = f2b(0.1f * zv);
                gp[idx] = f2b(di * zv);
            }
        }
    }
}

// ---------- propagation: persistent blocks, XCD-affine feature halves ----------
// Half h buffers are 64 B rows (32 bf16). 4 threads/node x 16 B. Blocks prefer
// h = XCC_ID & 1 (local-L2 gathers), steal the other half when empty.
template <int LAST>
__global__ __launch_bounds__(256) void prop_kernel(const unsigned short* __restrict__ gi0,
                                                   const unsigned short* __restrict__ gi1,
                                                   const unsigned short* __restrict__ xbh0,
                                                   const unsigned short* __restrict__ xbh1,
                                                   unsigned short* __restrict__ go0,
                                                   unsigned short* __restrict__ go1,
                                                   float* __restrict__ out,
                                                   const int* __restrict__ ofs,
                                                   const int* __restrict__ csr_src,
                                                   const float* __restrict__ dinv,
                                                   int* __restrict__ cnt, int n) {
    __shared__ int sc;
    unsigned int xcd;
    asm("s_getreg_b32 %0, hwreg(HW_REG_XCC_ID)" : "=s"(xcd));
    const int t = threadIdx.x;
    const int p = t & 3;        // 16B feature part within half
    const int nl = t >> 2;      // node-local 0..63
    const int nchunks = (n + 63) >> 6;
    const size_t poff = (size_t)p * 8;

    for (int pass = 0; pass < 2; ++pass) {
        const int h = ((int)xcd & 1) ^ pass;
        const unsigned short* gi = h ? gi1 : gi0;
        const unsigned short* xbh = h ? xbh1 : xbh0;
        unsigned short* go = h ? go1 : go0;
        for (;;) {
            if (t == 0) sc = atomicAdd(&cnt[h], 1);
            __syncthreads();
            int chunk = sc;
            __syncthreads();
            if (chunk >= nchunks) break;
            int node = (chunk << 6) + nl;
            if (node < n) {
                int beg = ofs[node];
                int end = ofs[node + 1];
                float acc[8];
#pragma unroll
                for (int j = 0; j < 8; ++j) acc[j] = 0.f;
                int e = beg;
                for (; e + 3 < end; e += 4) {
                    int s0 = csr_src[e];
                    int s1 = csr_src[e + 1];
                    int s2 = csr_src[e + 2];
                    int s3 = csr_src[e + 3];
                    ushort8 a = *(const ushort8*)(gi + ((size_t)s0 << 5) + poff);
                    ushort8 b = *(const ushort8*)(gi + ((size_t)s1 << 5) + poff);
                    ushort8 cc = *(const ushort8*)(gi + ((size_t)s2 << 5) + poff);
                    ushort8 d = *(const ushort8*)(gi + ((size_t)s3 << 5) + poff);
#pragma unroll
                    for (int j = 0; j < 8; ++j) acc[j] += b2f(a[j]);
#pragma unroll
                    for (int j = 0; j < 8; ++j) acc[j] += b2f(b[j]);
#pragma unroll
                    for (int j = 0; j < 8; ++j) acc[j] += b2f(cc[j]);
#pragma unroll
                    for (int j = 0; j < 8; ++j) acc[j] += b2f(d[j]);
                }
                for (; e < end; ++e) {
                    int s0 = csr_src[e];
                    ushort8 a = *(const ushort8*)(gi + ((size_t)s0 << 5) + poff);
#pragma unroll
                    for (int j = 0; j < 8; ++j) acc[j] += b2f(a[j]);
                }
                {  // self-loop
                    ushort8 a = *(const ushort8*)(gi + ((size_t)node << 5) + poff);
#pragma unroll
                    for (int j = 0; j < 8; ++j) acc[j] += b2f(a[j]);
                }
                float di = dinv[node];
                ushort8 xv = *(const ushort8*)(xbh + ((size_t)node << 5) + poff);
                float res[8];
#pragma unroll
                for (int j = 0; j < 8; ++j) res[j] = 0.9f * di * acc[j] + b2f(xv[j]);
                if (LAST) {
                    float4* o4 = (float4*)(out + (size_t)node * OUTF + ((size_t)h << 5) + poff);
                    o4[0] = make_float4(res[0], res[1], res[2], res[3]);
                    o4[1] = make_float4(res[4], res[5], res[6], res[7]);
                } else {
                    ushort8 o;
#pragma unroll
                    for (int j = 0; j < 8; ++j) o[j] = f2b(di * res[j]);
                    *(ushort8*)(go + ((size_t)node << 5) + poff) = o;
                }
            }
        }
    }
}

extern "C" void kernel_launch(void* const* d_in, const int* in_sizes, int n_in,
                              void* d_out, int out_size, void* d_ws, size_t ws_size,
                              hipStream_t stream) {
    const float* x = (const float*)d_in[0];
    const void* ei = d_in[1];
    const float* w1 = (const float*)d_in[2];
    const float* b1 = (const float*)d_in[3];
    const float* w2 = (const float*)d_in[4];
    const float* b2 = (const float*)d_in[5];
    float* out = (float*)d_out;

    int n = in_sizes[0] / HIDDEN;              // 100000
    long long E = (long long)in_sizes[1] / 2;  // 3200000
    int nb = (n + 255) >> 8;                   // 391 buckets

    char* ws = (char*)d_ws;
    size_t off = 0;
    auto alloc = [&](size_t bytes) {
        void* p = ws + off;
        off += (bytes + 511) & ~(size_t)511;
        return p;
    };
    size_t HBYTES = (size_t)n * 32 * 2;  // one half-buffer: 6.4 MB
    unsigned short* xbh0 = (unsigned short*)alloc(HBYTES);
    unsigned short* xbh1 = (unsigned short*)alloc(HBYTES);
    size_t gmark = off;
    unsigned short* gA0 = (unsigned short*)alloc(HBYTES);
    unsigned short* gA1 = (unsigned short*)alloc(HBYTES);
    unsigned short* gB0 = (unsigned short*)alloc(HBYTES);
    unsigned short* gB1 = (unsigned short*)alloc(HBYTES);
    unsigned int* pairs = (unsigned int*)(ws + gmark);  // 12.8 MB, aliases gA* (dead pre-MLP)
    float* dinv = (float*)alloc((size_t)n * 4);
    int* ofs = (int*)alloc((size_t)(n + 1) * 4);
    int* csr_src = (int*)alloc((size_t)E * 4);
    int* bh = (int*)alloc((size_t)512 * NB_BLK * 4);
    int* pre = (int*)alloc((size_t)512 * NB_BLK * 4);
    int* btot = (int*)alloc(512 * 4);
    int* bofs = (int*)alloc(513 * 4);
    unsigned short* w1p = (unsigned short*)alloc(65536 * 2);
    unsigned short* w2p = (unsigned short*)alloc(16384 * 2);
    int* cnt = (int*)alloc(32 * 4);  // 10 iters x 2 halves (+pad)

    hipMemsetAsync(cnt, 0, 32 * 4, stream);

    pack_w_kernel<<<40, 256, 0, stream>>>(w1, w2, w1p, w2p);

    part_hist_kernel<<<NB_BLK, 256, 0, stream>>>(ei, E, bh, n, nb);
    part_colscan_kernel<<<nb, NB_BLK, 0, stream>>>(bh, pre, btot);
    part_bscan_kernel<<<1, 512, 0, stream>>>(btot, bofs, nb);
    part_scatter_kernel<<<NB_BLK, 256, 0, stream>>>(ei, E, bofs, pre, pairs, n, nb);
    csr_bucket_kernel<<<nb, 256, 0, stream>>>(pairs, bofs, ofs, dinv, csr_src, n, nb);

    mlp_mfma_kernel<<<(n + 63) / 64, 512, 0, stream>>>(x, w1p, b1, w2p, b2, dinv, xbh0, xbh1,
                                                       gA0, gA1, n);

    const int PROP_BLOCKS = 2048;
    for (int k = 0; k < 10; ++k) {
        const unsigned short* gi0 = (k & 1) ? gB0 : gA0;
        const unsigned short* gi1 = (k & 1) ? gB1 : gA1;
        unsigned short* go0 = (k & 1) ? gA0 : gB0;
        unsigned short* go1 = (k & 1) ? gA1 : gB1;
        if (k == 9) {
            prop_kernel<1><<<PROP_BLOCKS, 256, 0, stream>>>(gi0, gi1, xbh0, xbh1, nullptr,
                                                            nullptr, out, ofs, csr_src, dinv,
                                                            cnt + k * 2, n);
        } else {
            prop_kernel<0><<<PROP_BLOCKS, 256, 0, stream>>>(gi0, gi1, xbh0, xbh1, go0, go1,
                                                            nullptr, ofs, csr_src, dinv,
                                                            cnt + k * 2, n);
        }
    }
}

// Round 11
// 684.189 us; speedup vs baseline: 2.2098x; 2.2098x over previous
//
#include <hip/hip_runtime.h>
#include <hip/hip_bf16.h>

// APPNP: z = MLP(x) (bf16 MFMA, pre-packed weights, 8-wave blocks, 2-deep x
// prefetch); then 10x propagation x_{k+1} = 0.9 * A_hat x_k + 0.1 * z over
// bf16 128-B rows (one 128-B transaction per edge -- transaction-rate bound).
// CSR built via contention-free two-pass bucket partition (packed uint pairs).

#define HIDDEN 256
#define OUTF   64
#define NB_BLK 256

typedef __attribute__((ext_vector_type(8))) unsigned short ushort8;
typedef __attribute__((ext_vector_type(8))) short short8v;
typedef __attribute__((ext_vector_type(4))) float f32x4;

__device__ inline float b2f(unsigned short u) {
    union { unsigned int i; float f; } c;
    c.i = ((unsigned int)u) << 16;
    return c.f;
}
__device__ inline unsigned short f2b(float f) {
    union { float f; unsigned int i; } c;
    c.f = f;
    unsigned int x = c.i;
    unsigned int r = (x + 0x7fff + ((x >> 16) & 1)) >> 16;  // RNE
    return (unsigned short)r;
}
__device__ inline short8v cvt8v(float4 A, float4 B) {
    short8v o;
    o[0] = (short)f2b(A.x); o[1] = (short)f2b(A.y);
    o[2] = (short)f2b(A.z); o[3] = (short)f2b(A.w);
    o[4] = (short)f2b(B.x); o[5] = (short)f2b(B.y);
    o[6] = (short)f2b(B.z); o[7] = (short)f2b(B.w);
    return o;
}
__device__ inline short8v cvt8(const float* s) {
    return cvt8v(((const float4*)s)[0], ((const float4*)s)[1]);
}

// ---------- int64/int32 edge-index hedge ----------
__device__ inline bool detect_i64(const int* __restrict__ p) {
    int acc = 0;
#pragma unroll
    for (int i = 0; i < 16; ++i) acc |= p[2 * i + 1];
    return acc == 0;
}
__device__ inline int load_idx(const void* eiv, long long flat, bool is64) {
    if (is64) return (int)((const long long*)eiv)[flat];
    return ((const int*)eiv)[flat];
}

// ---------- P0: per-block bucket histogram ----------
__global__ __launch_bounds__(256) void part_hist_kernel(const void* __restrict__ eiv,
                                                        long long E, int* __restrict__ bh,
                                                        int n, int nb) {
    __shared__ int hist[512];
    bool is64 = detect_i64((const int*)eiv);
    int t = threadIdx.x, b = blockIdx.x;
    for (int i = t; i < 512; i += 256) hist[i] = 0;
    __syncthreads();
    long long chunk = (E + NB_BLK - 1) / NB_BLK;
    long long beg = (long long)b * chunk, end = min(E, beg + chunk);
    for (long long e = beg + t; e < end; e += 256) {
        int c = load_idx(eiv, E + e, is64);
        if ((unsigned)c < (unsigned)n) atomicAdd(&hist[c >> 8], 1);
    }
    __syncthreads();
    for (int i = t; i < nb; i += 256) bh[i * NB_BLK + b] = hist[i];
}

// ---------- P1a: per-bucket scan over blocks ----------
__global__ __launch_bounds__(256) void part_colscan_kernel(const int* __restrict__ bh,
                                                           int* __restrict__ pre,
                                                           int* __restrict__ btot) {
    __shared__ int s[NB_BLK];
    int g = blockIdx.x, t = threadIdx.x;
    int v = bh[g * NB_BLK + t];
    s[t] = v;
    __syncthreads();
    for (int o = 1; o < NB_BLK; o <<= 1) {
        int tv = (t >= o) ? s[t - o] : 0;
        __syncthreads();
        s[t] += tv;
        __syncthreads();
    }
    pre[g * NB_BLK + t] = s[t] - v;
    if (t == NB_BLK - 1) btot[g] = s[t];
}

// ---------- P1b: scan over buckets ----------
__global__ __launch_bounds__(512) void part_bscan_kernel(const int* __restrict__ btot,
                                                         int* __restrict__ bofs, int nb) {
    __shared__ int s[512];
    int t = threadIdx.x;
    int v = (t < nb) ? btot[t] : 0;
    s[t] = v;
    __syncthreads();
    for (int o = 1; o < 512; o <<= 1) {
        int tv = (t >= o) ? s[t - o] : 0;
        __syncthreads();
        s[t] += tv;
        __syncthreads();
    }
    if (t < nb) bofs[t] = s[t] - v;
    if (t == 511) bofs[nb] = s[511];
}

// ---------- P2: stable scatter of packed pairs ((c&255)<<24 | r) ----------
__global__ __launch_bounds__(256) void part_scatter_kernel(const void* __restrict__ eiv,
                                                           long long E,
                                                           const int* __restrict__ bofs,
                                                           const int* __restrict__ pre,
                                                           unsigned int* __restrict__ pairs,
                                                           int n, int nb) {
    __shared__ int cur[512];
    bool is64 = detect_i64((const int*)eiv);
    int t = threadIdx.x, b = blockIdx.x;
    for (int i = t; i < nb; i += 256) cur[i] = bofs[i] + pre[i * NB_BLK + b];
    __syncthreads();
    long long chunk = (E + NB_BLK - 1) / NB_BLK;
    long long beg = (long long)b * chunk, end = min(E, beg + chunk);
    for (long long e = beg + t; e < end; e += 256) {
        int r = load_idx(eiv, e, is64);
        int c = load_idx(eiv, E + e, is64);
        if ((unsigned)c >= (unsigned)n || (unsigned)r >= (unsigned)n) continue;
        int pos = atomicAdd(&cur[c >> 8], 1);
        pairs[pos] = ((unsigned int)(c & 255) << 24) | (unsigned int)r;
    }
}

// ---------- P3: per-bucket CSR build + dinv ----------
__global__ __launch_bounds__(256) void csr_bucket_kernel(const unsigned int* __restrict__ pairs,
                                                         const int* __restrict__ bofs,
                                                         int* __restrict__ ofs,
                                                         float* __restrict__ dinv,
                                                         int* __restrict__ csr_src,
                                                         int n, int nb) {
    __shared__ int hist[256];
    __shared__ int scn[256];
    int b = blockIdx.x;
    int t = threadIdx.x;
    int node0 = b << 8;
    int cnt = min(256, n - node0);

    hist[t] = 0;
    __syncthreads();
    int beg = bofs[b], end = bofs[b + 1];
    for (int e = beg + t; e < end; e += 256) atomicAdd(&hist[pairs[e] >> 24], 1);
    __syncthreads();
    int v = hist[t];
    scn[t] = v;
    __syncthreads();
    for (int o = 1; o < 256; o <<= 1) {
        int tv = (t >= o) ? scn[t - o] : 0;
        __syncthreads();
        scn[t] += tv;
        __syncthreads();
    }
    int excl = scn[t] - v;
    if (t < cnt) {
        ofs[node0 + t] = beg + excl;
        dinv[node0 + t] = rsqrtf((float)(v + 1));
    }
    if (b == nb - 1 && t == 0) ofs[n] = end;
    __syncthreads();
    hist[t] = beg + excl;
    __syncthreads();
    for (int e = beg + t; e < end; e += 256) {
        unsigned int pr = pairs[e];
        int pos = atomicAdd(&hist[pr >> 24], 1);
        csr_src[pos] = (int)(pr & 0xFFFFFFu);
    }
}

// ---------- pack w1/w2 into bf16 fragment-linear layouts ----------
__global__ __launch_bounds__(256) void pack_w_kernel(const float* __restrict__ w1,
                                                     const float* __restrict__ w2,
                                                     unsigned short* __restrict__ w1p,
                                                     unsigned short* __restrict__ w2p) {
    int id = blockIdx.x * 256 + threadIdx.x;
    if (id < 8192) {
        int ks = id >> 10, rem = id & 1023;
        int f = rem >> 2, kg = rem & 3;
        short8v o = cvt8(w1 + (size_t)f * HIDDEN + ks * 32 + kg * 8);
        *(short8v*)(w1p + ((size_t)(ks * 1024 + (f >> 4) * 64 + kg * 16 + (f & 15)) << 3)) = o;
    } else if (id < 8192 + 2048) {
        int q = id - 8192;
        int j = q >> 5, kslot = q & 31;
        short8v o = cvt8(w2 + (size_t)j * HIDDEN + kslot * 8);
        *(short8v*)(w2p +
                    ((size_t)((j >> 4) * 512 + (kslot >> 2) * 64 + (kslot & 3) * 16 + (j & 15))
                     << 3)) = o;
    }
}

// ---------- fused MFMA MLP, 8 waves, 2-deep x prefetch ----------
__global__ __launch_bounds__(512) void mlp_mfma_kernel(const float* __restrict__ x,
                                                       const unsigned short* __restrict__ w1p,
                                                       const float* __restrict__ b1,
                                                       const unsigned short* __restrict__ w2p,
                                                       const float* __restrict__ b2,
                                                       const float* __restrict__ dinv,
                                                       unsigned short* __restrict__ xb0,
                                                       unsigned short* __restrict__ g0, int n) {
    __shared__ __align__(16) union {
        struct { unsigned short w1s[8192]; unsigned short xs[2048]; } p1;  // 20 KB
        unsigned short h[64 * 264];                                        // 33 KB
    } u;

    const int t = threadIdx.x;   // 0..511
    const int w = t >> 6;        // wave 0..7
    const int l = t & 63;
    const int c = l & 15, g = l >> 4;
    const int node0 = blockIdx.x * 64;

    const bool xrole = (t < 256);
    const int sm = t >> 2, skg = t & 3;
    const int snode = node0 + sm;
    const int wu0 = t - 256;
    const int xunit = ((sm >> 4) * 64 + skg * 16 + (sm & 15)) << 3;

    f32x4 acc[4][2];
#pragma unroll
    for (int a = 0; a < 4; ++a)
#pragma unroll
        for (int b = 0; b < 2; ++b) acc[a][b] = (f32x4)0.f;

    float4 pxa0 = make_float4(0.f, 0.f, 0.f, 0.f), pxb0 = pxa0;
    float4 pxa1 = pxa0, pxb1 = pxa0;
    short8v pw[4];

    auto loadx = [&](int ks, float4& A, float4& B) {
        if (snode < n) {
            const float4* xp = (const float4*)(x + (size_t)snode * HIDDEN + ks * 32 + skg * 8);
            A = xp[0];
            B = xp[1];
        }
    };
    auto loadw = [&](int ks) {
        const unsigned short* wsrc = w1p + (size_t)ks * 8192;
#pragma unroll
        for (int i = 0; i < 4; ++i)
            pw[i] = *(const short8v*)(wsrc + ((size_t)(wu0 + i * 256) << 3));
    };
    auto mfma_step = [&]() {
        short8v af[4], bf[2];
#pragma unroll
        for (int mt = 0; mt < 4; ++mt)
            af[mt] = *(const short8v*)&u.p1.xs[(mt * 64 + l) << 3];
#pragma unroll
        for (int j = 0; j < 2; ++j)
            bf[j] = *(const short8v*)&u.p1.w1s[((w * 2 + j) * 64 + l) << 3];
#pragma unroll
        for (int mt = 0; mt < 4; ++mt)
#pragma unroll
            for (int j = 0; j < 2; ++j)
                acc[mt][j] =
                    __builtin_amdgcn_mfma_f32_16x16x32_bf16(af[mt], bf[j], acc[mt][j], 0, 0, 0);
    };
    auto wwrite = [&]() {
#pragma unroll
        for (int i = 0; i < 4; ++i)
            *(short8v*)&u.p1.w1s[(wu0 + i * 256) << 3] = pw[i];
    };

    if (xrole) {
        loadx(0, pxa0, pxb0);
        loadx(1, pxa1, pxb1);
    } else {
        loadw(0);
    }

    for (int ks = 0; ks < 8; ks += 2) {
        if (xrole) *(short8v*)&u.p1.xs[xunit] = cvt8v(pxa0, pxb0);
        else wwrite();
        __syncthreads();
        if (xrole) {
            if (ks + 2 < 8) loadx(ks + 2, pxa0, pxb0);
        } else {
            loadw(ks + 1);
        }
        mfma_step();
        __syncthreads();
        if (xrole) *(short8v*)&u.p1.xs[xunit] = cvt8v(pxa1, pxb1);
        else wwrite();
        __syncthreads();
        if (xrole) {
            if (ks + 3 < 8) loadx(ks + 3, pxa1, pxb1);
        } else {
            if (ks + 2 < 8) loadw(ks + 2);
        }
        mfma_step();
        __syncthreads();
    }

#pragma unroll
    for (int j = 0; j < 2; ++j) {
        int col = w * 32 + j * 16 + c;
        float b1v = b1[col];
#pragma unroll
        for (int mt = 0; mt < 4; ++mt)
#pragma unroll
            for (int r = 0; r < 4; ++r) {
                int row = mt * 16 + g * 4 + r;
                u.h[row * 264 + col] = f2b(fmaxf(acc[mt][j][r] + b1v, 0.f));
            }
    }
    __syncthreads();

    const int rt = w >> 1;
    const int cb = (w & 1) * 2;
    f32x4 acc2[2];
#pragma unroll
    for (int j = 0; j < 2; ++j) acc2[j] = (f32x4)0.f;
#pragma unroll
    for (int ks = 0; ks < 8; ++ks) {
        short8v a2 = *(const short8v*)&u.h[(rt * 16 + c) * 264 + ks * 32 + g * 8];
#pragma unroll
        for (int j = 0; j < 2; ++j) {
            short8v bv = *(const short8v*)(w2p + ((size_t)((cb + j) * 512 + ks * 64 + l) << 3));
            acc2[j] = __builtin_amdgcn_mfma_f32_16x16x32_bf16(a2, bv, acc2[j], 0, 0, 0);
        }
    }
#pragma unroll
    for (int j = 0; j < 2; ++j) {
        int col = (cb + j) * 16 + c;
        float bb = b2[col];
#pragma unroll
        for (int r = 0; r < 4; ++r) {
            int node = node0 + rt * 16 + g * 4 + r;
            if (node < n) {
                float zv = acc2[j][r] + bb;
                float di = dinv[node];
                xb0[(size_t)node * OUTF + col] = f2b(0.1f * zv);
                g0[(size_t)node * OUTF + col] = f2b(di * zv);
            }
        }
    }
}

// ---------- propagation: 8 threads/node, 16B/thread, 4-deep unroll ----------
// One random 128-B row transaction per edge; transaction-rate bound.
template <int LAST>
__global__ __launch_bounds__(256, 8) void prop_kernel(const unsigned short* __restrict__ gk,
                                                      const unsigned short* __restrict__ xb0,
                                                      unsigned short* __restrict__ gn,
                                                      float* __restrict__ out,
                                                      const int* __restrict__ ofs,
                                                      const int* __restrict__ csr_src,
                                                      const float* __restrict__ dinv, int n) {
    int gid = blockIdx.x * 256 + threadIdx.x;
    int node = gid >> 3;
    int part = gid & 7;
    if (node >= n) return;

    int beg = ofs[node];
    int end = ofs[node + 1];
    float di = dinv[node];

    float acc[8];
#pragma unroll
    for (int j = 0; j < 8; ++j) acc[j] = 0.f;

    const size_t poff = (size_t)part * 8;
    int e = beg;
    for (; e + 3 < end; e += 4) {
        int s0 = csr_src[e];
        int s1 = csr_src[e + 1];
        int s2 = csr_src[e + 2];
        int s3 = csr_src[e + 3];
        ushort8 a = *(const ushort8*)(gk + ((size_t)s0 << 6) + poff);
        ushort8 b = *(const ushort8*)(gk + ((size_t)s1 << 6) + poff);
        ushort8 cc = *(const ushort8*)(gk + ((size_t)s2 << 6) + poff);
        ushort8 d = *(const ushort8*)(gk + ((size_t)s3 << 6) + poff);
#pragma unroll
        for (int j = 0; j < 8; ++j) acc[j] += b2f(a[j]);
#pragma unroll
        for (int j = 0; j < 8; ++j) acc[j] += b2f(b[j]);
#pragma unroll
        for (int j = 0; j < 8; ++j) acc[j] += b2f(cc[j]);
#pragma unroll
        for (int j = 0; j < 8; ++j) acc[j] += b2f(d[j]);
    }
    for (; e < end; ++e) {
        int s0 = csr_src[e];
        ushort8 a = *(const ushort8*)(gk + ((size_t)s0 << 6) + poff);
#pragma unroll
        for (int j = 0; j < 8; ++j) acc[j] += b2f(a[j]);
    }
    {
        ushort8 a = *(const ushort8*)(gk + ((size_t)node << 6) + poff);
#pragma unroll
        for (int j = 0; j < 8; ++j) acc[j] += b2f(a[j]);
    }

    ushort8 xv = *(const ushort8*)(xb0 + ((size_t)node << 6) + poff);
    float res[8];
#pragma unroll
    for (int j = 0; j < 8; ++j) res[j] = 0.9f * di * acc[j] + b2f(xv[j]);

    if (LAST) {
        float4* o4 = (float4*)(out + (size_t)node * OUTF + poff);
        o4[0] = make_float4(res[0], res[1], res[2], res[3]);
        o4[1] = make_float4(res[4], res[5], res[6], res[7]);
    } else {
        ushort8 o;
#pragma unroll
        for (int j = 0; j < 8; ++j) o[j] = f2b(di * res[j]);
        *(ushort8*)(gn + ((size_t)node << 6) + poff) = o;
    }
}

extern "C" void kernel_launch(void* const* d_in, const int* in_sizes, int n_in,
                              void* d_out, int out_size, void* d_ws, size_t ws_size,
                              hipStream_t stream) {
    const float* x = (const float*)d_in[0];
    const void* ei = d_in[1];
    const float* w1 = (const float*)d_in[2];
    const float* b1 = (const float*)d_in[3];
    const float* w2 = (const float*)d_in[4];
    const float* b2 = (const float*)d_in[5];
    float* out = (float*)d_out;

    int n = in_sizes[0] / HIDDEN;              // 100000
    long long E = (long long)in_sizes[1] / 2;  // 3200000
    int nb = (n + 255) >> 8;                   // 391 buckets

    char* ws = (char*)d_ws;
    size_t off = 0;
    auto alloc = [&](size_t bytes) {
        void* p = ws + off;
        off += (bytes + 511) & ~(size_t)511;
        return p;
    };
    unsigned short* xb0 = (unsigned short*)alloc((size_t)n * OUTF * 2);  // 12.8 MB
    size_t gmark = off;
    unsigned short* gA = (unsigned short*)alloc((size_t)n * OUTF * 2);   // 12.8 MB
    unsigned short* gB = (unsigned short*)alloc((size_t)n * OUTF * 2);   // 12.8 MB
    unsigned int* pairs = (unsigned int*)(ws + gmark);  // 12.8 MB, aliases gA/gB (dead pre-MLP)
    float* dinv = (float*)alloc((size_t)n * 4);
    int* ofs = (int*)alloc((size_t)(n + 1) * 4);
    int* csr_src = (int*)alloc((size_t)E * 4);                           // 12.8 MB
    int* bh = (int*)alloc((size_t)512 * NB_BLK * 4);
    int* pre = (int*)alloc((size_t)512 * NB_BLK * 4);
    int* btot = (int*)alloc(512 * 4);
    int* bofs = (int*)alloc(513 * 4);
    unsigned short* w1p = (unsigned short*)alloc(65536 * 2);
    unsigned short* w2p = (unsigned short*)alloc(16384 * 2);

    pack_w_kernel<<<40, 256, 0, stream>>>(w1, w2, w1p, w2p);

    part_hist_kernel<<<NB_BLK, 256, 0, stream>>>(ei, E, bh, n, nb);
    part_colscan_kernel<<<nb, NB_BLK, 0, stream>>>(bh, pre, btot);
    part_bscan_kernel<<<1, 512, 0, stream>>>(btot, bofs, nb);
    part_scatter_kernel<<<NB_BLK, 256, 0, stream>>>(ei, E, bofs, pre, pairs, n, nb);
    csr_bucket_kernel<<<nb, 256, 0, stream>>>(pairs, bofs, ofs, dinv, csr_src, n, nb);

    mlp_mfma_kernel<<<(n + 63) / 64, 512, 0, stream>>>(x, w1p, b1, w2p, b2, dinv, xb0, gA, n);

    int prop_blocks = (int)(((size_t)n * 8 + 255) / 256);
    for (int k = 0; k < 10; ++k) {
        const unsigned short* gin = (k & 1) ? gB : gA;
        unsigned short* gout = (k & 1) ? gA : gB;
        if (k == 9) {
            prop_kernel<1><<<prop_blocks, 256, 0, stream>>>(gin, xb0, nullptr, out, ofs,
                                                            csr_src, dinv, n);
        } else {
            prop_kernel<0><<<prop_blocks, 256, 0, stream>>>(gin, xb0, gout, nullptr, ofs,
                                                            csr_src, dinv, n);
        }
    }
}

// Round 12
// 678.628 us; speedup vs baseline: 2.2279x; 1.0082x over previous
//
#include <hip/hip_runtime.h>
#include <hip/hip_bf16.h>

// APPNP: z = MLP(x) (bf16 MFMA; w1/w2 fragments read direct from L2); then 10x
// propagation x_{k+1} = 0.9 * A_hat x_k + 0.1 * z over bf16 128-B rows
// (one random 128-B row-gather per edge -- L2-miss/L3 service-rate bound).
// CSR built via contention-free two-pass bucket partition (packed uint pairs);
// weight pre-pack fused into the histogram kernel.

#define HIDDEN 256
#define OUTF   64
#define NB_BLK 256

typedef __attribute__((ext_vector_type(8))) unsigned short ushort8;
typedef __attribute__((ext_vector_type(8))) short short8v;
typedef __attribute__((ext_vector_type(4))) float f32x4;

__device__ inline float b2f(unsigned short u) {
    union { unsigned int i; float f; } c;
    c.i = ((unsigned int)u) << 16;
    return c.f;
}
__device__ inline unsigned short f2b(float f) {
    union { float f; unsigned int i; } c;
    c.f = f;
    unsigned int x = c.i;
    unsigned int r = (x + 0x7fff + ((x >> 16) & 1)) >> 16;  // RNE
    return (unsigned short)r;
}
__device__ inline short8v cvt8v(float4 A, float4 B) {
    short8v o;
    o[0] = (short)f2b(A.x); o[1] = (short)f2b(A.y);
    o[2] = (short)f2b(A.z); o[3] = (short)f2b(A.w);
    o[4] = (short)f2b(B.x); o[5] = (short)f2b(B.y);
    o[6] = (short)f2b(B.z); o[7] = (short)f2b(B.w);
    return o;
}
__device__ inline short8v cvt8(const float* s) {
    return cvt8v(((const float4*)s)[0], ((const float4*)s)[1]);
}

// ---------- int64/int32 edge-index hedge ----------
__device__ inline bool detect_i64(const int* __restrict__ p) {
    int acc = 0;
#pragma unroll
    for (int i = 0; i < 16; ++i) acc |= p[2 * i + 1];
    return acc == 0;
}
__device__ inline int load_idx(const void* eiv, long long flat, bool is64) {
    if (is64) return (int)((const long long*)eiv)[flat];
    return ((const int*)eiv)[flat];
}

// ---------- P0: per-block bucket histogram (+ fused weight pre-pack) ----------
__global__ __launch_bounds__(256) void part_hist_kernel(const void* __restrict__ eiv,
                                                        long long E, int* __restrict__ bh,
                                                        int n, int nb,
                                                        const float* __restrict__ w1,
                                                        const float* __restrict__ w2,
                                                        unsigned short* __restrict__ w1p,
                                                        unsigned short* __restrict__ w2p) {
    // fused pack: blocks 0..39 (ids 0..10239)
    if (blockIdx.x < 40) {
        int id = blockIdx.x * 256 + threadIdx.x;
        if (id < 8192) {
            int ks = id >> 10, rem = id & 1023;
            int f = rem >> 2, kg = rem & 3;
            short8v o = cvt8(w1 + (size_t)f * HIDDEN + ks * 32 + kg * 8);
            *(short8v*)(w1p + ((size_t)(ks * 1024 + (f >> 4) * 64 + kg * 16 + (f & 15)) << 3)) = o;
        } else if (id < 8192 + 2048) {
            int q = id - 8192;
            int j = q >> 5, kslot = q & 31;
            short8v o = cvt8(w2 + (size_t)j * HIDDEN + kslot * 8);
            *(short8v*)(w2p + ((size_t)((j >> 4) * 512 + (kslot >> 2) * 64 + (kslot & 3) * 16 +
                                        (j & 15))
                               << 3)) = o;
        }
    }

    __shared__ int hist[512];
    bool is64 = detect_i64((const int*)eiv);
    int t = threadIdx.x, b = blockIdx.x;
    for (int i = t; i < 512; i += 256) hist[i] = 0;
    __syncthreads();
    long long chunk = (E + NB_BLK - 1) / NB_BLK;
    long long beg = (long long)b * chunk, end = min(E, beg + chunk);
    for (long long e = beg + t; e < end; e += 256) {
        int c = load_idx(eiv, E + e, is64);
        if ((unsigned)c < (unsigned)n) atomicAdd(&hist[c >> 8], 1);
    }
    __syncthreads();
    for (int i = t; i < nb; i += 256) bh[i * NB_BLK + b] = hist[i];
}

// ---------- P1a: per-bucket scan over blocks ----------
__global__ __launch_bounds__(256) void part_colscan_kernel(const int* __restrict__ bh,
                                                           int* __restrict__ pre,
                                                           int* __restrict__ btot) {
    __shared__ int s[NB_BLK];
    int g = blockIdx.x, t = threadIdx.x;
    int v = bh[g * NB_BLK + t];
    s[t] = v;
    __syncthreads();
    for (int o = 1; o < NB_BLK; o <<= 1) {
        int tv = (t >= o) ? s[t - o] : 0;
        __syncthreads();
        s[t] += tv;
        __syncthreads();
    }
    pre[g * NB_BLK + t] = s[t] - v;
    if (t == NB_BLK - 1) btot[g] = s[t];
}

// ---------- P1b: scan over buckets ----------
__global__ __launch_bounds__(512) void part_bscan_kernel(const int* __restrict__ btot,
                                                         int* __restrict__ bofs, int nb) {
    __shared__ int s[512];
    int t = threadIdx.x;
    int v = (t < nb) ? btot[t] : 0;
    s[t] = v;
    __syncthreads();
    for (int o = 1; o < 512; o <<= 1) {
        int tv = (t >= o) ? s[t - o] : 0;
        __syncthreads();
        s[t] += tv;
        __syncthreads();
    }
    if (t < nb) bofs[t] = s[t] - v;
    if (t == 511) bofs[nb] = s[511];
}

// ---------- P2: stable scatter of packed pairs ((c&255)<<24 | r) ----------
__global__ __launch_bounds__(256) void part_scatter_kernel(const void* __restrict__ eiv,
                                                           long long E,
                                                           const int* __restrict__ bofs,
                                                           const int* __restrict__ pre,
                                                           unsigned int* __restrict__ pairs,
                                                           int n, int nb) {
    __shared__ int cur[512];
    bool is64 = detect_i64((const int*)eiv);
    int t = threadIdx.x, b = blockIdx.x;
    for (int i = t; i < nb; i += 256) cur[i] = bofs[i] + pre[i * NB_BLK + b];
    __syncthreads();
    long long chunk = (E + NB_BLK - 1) / NB_BLK;
    long long beg = (long long)b * chunk, end = min(E, beg + chunk);
    for (long long e = beg + t; e < end; e += 256) {
        int r = load_idx(eiv, e, is64);
        int c = load_idx(eiv, E + e, is64);
        if ((unsigned)c >= (unsigned)n || (unsigned)r >= (unsigned)n) continue;
        int pos = atomicAdd(&cur[c >> 8], 1);
        pairs[pos] = ((unsigned int)(c & 255) << 24) | (unsigned int)r;
    }
}

// ---------- P3: per-bucket CSR build + dinv ----------
__global__ __launch_bounds__(256) void csr_bucket_kernel(const unsigned int* __restrict__ pairs,
                                                         const int* __restrict__ bofs,
                                                         int* __restrict__ ofs,
                                                         float* __restrict__ dinv,
                                                         int* __restrict__ csr_src,
                                                         int n, int nb) {
    __shared__ int hist[256];
    __shared__ int scn[256];
    int b = blockIdx.x;
    int t = threadIdx.x;
    int node0 = b << 8;
    int cnt = min(256, n - node0);

    hist[t] = 0;
    __syncthreads();
    int beg = bofs[b], end = bofs[b + 1];
    for (int e = beg + t; e < end; e += 256) atomicAdd(&hist[pairs[e] >> 24], 1);
    __syncthreads();
    int v = hist[t];
    scn[t] = v;
    __syncthreads();
    for (int o = 1; o < 256; o <<= 1) {
        int tv = (t >= o) ? scn[t - o] : 0;
        __syncthreads();
        scn[t] += tv;
        __syncthreads();
    }
    int excl = scn[t] - v;
    if (t < cnt) {
        ofs[node0 + t] = beg + excl;
        dinv[node0 + t] = rsqrtf((float)(v + 1));
    }
    if (b == nb - 1 && t == 0) ofs[n] = end;
    __syncthreads();
    hist[t] = beg + excl;
    __syncthreads();
    for (int e = beg + t; e < end; e += 256) {
        unsigned int pr = pairs[e];
        int pos = atomicAdd(&hist[pr >> 24], 1);
        csr_src[pos] = (int)(pr & 0xFFFFFFu);
    }
}

// ---------- fused MFMA MLP, 8 waves; w1/w2 fragments direct from L2 ----------
// LDS: union{ xs 4KB (phase-1 x chunk), h 33KB (phase-2 A tile) }.
// Threads t<256 stage x (2-deep prefetch); w1p is 128 KB, L2-resident across
// all blocks, so B-fragments load straight from global.
__global__ __launch_bounds__(512) void mlp_mfma_kernel(const float* __restrict__ x,
                                                       const unsigned short* __restrict__ w1p,
                                                       const float* __restrict__ b1,
                                                       const unsigned short* __restrict__ w2p,
                                                       const float* __restrict__ b2,
                                                       const float* __restrict__ dinv,
                                                       unsigned short* __restrict__ xb0,
                                                       unsigned short* __restrict__ g0, int n) {
    __shared__ __align__(16) union {
        unsigned short xs[2048];     // 4 KB  (phase 1)
        unsigned short h[64 * 264];  // 33 KB (phase 2)
    } u;

    const int t = threadIdx.x;   // 0..511
    const int w = t >> 6;        // wave 0..7
    const int l = t & 63;
    const int c = l & 15, g = l >> 4;
    const int node0 = blockIdx.x * 64;

    const bool xrole = (t < 256);
    const int sm = t >> 2, skg = t & 3;
    const int snode = node0 + sm;
    const int xunit = ((sm >> 4) * 64 + skg * 16 + (sm & 15)) << 3;

    f32x4 acc[4][2];
#pragma unroll
    for (int a = 0; a < 4; ++a)
#pragma unroll
        for (int b = 0; b < 2; ++b) acc[a][b] = (f32x4)0.f;

    float4 pxa0 = make_float4(0.f, 0.f, 0.f, 0.f), pxb0 = pxa0;
    float4 pxa1 = pxa0, pxb1 = pxa0;

    auto loadx = [&](int ks, float4& A, float4& B) {
        if (snode < n) {
            const float4* xp = (const float4*)(x + (size_t)snode * HIDDEN + ks * 32 + skg * 8);
            A = xp[0];
            B = xp[1];
        }
    };
    auto mfma_step = [&](int ks) {
        const unsigned short* wsrc = w1p + ((size_t)ks << 13);
        short8v bf[2];
#pragma unroll
        for (int j = 0; j < 2; ++j)
            bf[j] = *(const short8v*)(wsrc + (((w * 2 + j) * 64 + l) << 3));
        short8v af[4];
#pragma unroll
        for (int mt = 0; mt < 4; ++mt)
            af[mt] = *(const short8v*)&u.xs[(mt * 64 + l) << 3];
#pragma unroll
        for (int mt = 0; mt < 4; ++mt)
#pragma unroll
            for (int j = 0; j < 2; ++j)
                acc[mt][j] =
                    __builtin_amdgcn_mfma_f32_16x16x32_bf16(af[mt], bf[j], acc[mt][j], 0, 0, 0);
    };

    if (xrole) {
        loadx(0, pxa0, pxb0);
        loadx(1, pxa1, pxb1);
    }

    for (int ks = 0; ks < 8; ks += 2) {
        if (xrole) *(short8v*)&u.xs[xunit] = cvt8v(pxa0, pxb0);
        __syncthreads();
        if (xrole && ks + 2 < 8) loadx(ks + 2, pxa0, pxb0);
        mfma_step(ks);
        __syncthreads();
        if (xrole) *(short8v*)&u.xs[xunit] = cvt8v(pxa1, pxb1);
        __syncthreads();
        if (xrole && ks + 3 < 8) loadx(ks + 3, pxa1, pxb1);
        mfma_step(ks + 1);
        __syncthreads();
    }

    // bias + relu -> h (xs dead after last barrier)
#pragma unroll
    for (int j = 0; j < 2; ++j) {
        int col = w * 32 + j * 16 + c;
        float b1v = b1[col];
#pragma unroll
        for (int mt = 0; mt < 4; ++mt)
#pragma unroll
            for (int r = 0; r < 4; ++r) {
                int row = mt * 16 + g * 4 + r;
                u.h[row * 264 + col] = f2b(fmaxf(acc[mt][j][r] + b1v, 0.f));
            }
    }
    __syncthreads();

    // phase 2: z = h @ w2.T + b2. Wave w: row-tile rt = w>>1, col-tiles (w&1)*2+{0,1}.
    const int rt = w >> 1;
    const int cb = (w & 1) * 2;
    f32x4 acc2[2];
#pragma unroll
    for (int j = 0; j < 2; ++j) acc2[j] = (f32x4)0.f;
#pragma unroll
    for (int ks = 0; ks < 8; ++ks) {
        short8v a2 = *(const short8v*)&u.h[(rt * 16 + c) * 264 + ks * 32 + g * 8];
#pragma unroll
        for (int j = 0; j < 2; ++j) {
            short8v bv = *(const short8v*)(w2p + ((size_t)((cb + j) * 512 + ks * 64 + l) << 3));
            acc2[j] = __builtin_amdgcn_mfma_f32_16x16x32_bf16(a2, bv, acc2[j], 0, 0, 0);
        }
    }
#pragma unroll
    for (int j = 0; j < 2; ++j) {
        int col = (cb + j) * 16 + c;
        float bb = b2[col];
#pragma unroll
        for (int r = 0; r < 4; ++r) {
            int node = node0 + rt * 16 + g * 4 + r;
            if (node < n) {
                float zv = acc2[j][r] + bb;
                float di = dinv[node];
                xb0[(size_t)node * OUTF + col] = f2b(0.1f * zv);
                g0[(size_t)node * OUTF + col] = f2b(di * zv);
            }
        }
    }
}

// ---------- propagation: 8 threads/node, 16B/thread, 4-deep unroll ----------
// One random 128-B row transaction per edge; L2-miss/L3 service-rate bound.
template <int LAST>
__global__ __launch_bounds__(256, 8) void prop_kernel(const unsigned short* __restrict__ gk,
                                                      const unsigned short* __restrict__ xb0,
                                                      unsigned short* __restrict__ gn,
                                                      float* __restrict__ out,
                                                      const int* __restrict__ ofs,
                                                      const int* __restrict__ csr_src,
                                                      const float* __restrict__ dinv, int n) {
    int gid = blockIdx.x * 256 + threadIdx.x;
    int node = gid >> 3;
    int part = gid & 7;
    if (node >= n) return;

    int beg = ofs[node];
    int end = ofs[node + 1];
    float di = dinv[node];

    float acc[8];
#pragma unroll
    for (int j = 0; j < 8; ++j) acc[j] = 0.f;

    const size_t poff = (size_t)part * 8;
    int e = beg;
    for (; e + 3 < end; e += 4) {
        int s0 = csr_src[e];
        int s1 = csr_src[e + 1];
        int s2 = csr_src[e + 2];
        int s3 = csr_src[e + 3];
        ushort8 a = *(const ushort8*)(gk + ((size_t)s0 << 6) + poff);
        ushort8 b = *(const ushort8*)(gk + ((size_t)s1 << 6) + poff);
        ushort8 cc = *(const ushort8*)(gk + ((size_t)s2 << 6) + poff);
        ushort8 d = *(const ushort8*)(gk + ((size_t)s3 << 6) + poff);
#pragma unroll
        for (int j = 0; j < 8; ++j) acc[j] += b2f(a[j]);
#pragma unroll
        for (int j = 0; j < 8; ++j) acc[j] += b2f(b[j]);
#pragma unroll
        for (int j = 0; j < 8; ++j) acc[j] += b2f(cc[j]);
#pragma unroll
        for (int j = 0; j < 8; ++j) acc[j] += b2f(d[j]);
    }
    for (; e < end; ++e) {
        int s0 = csr_src[e];
        ushort8 a = *(const ushort8*)(gk + ((size_t)s0 << 6) + poff);
#pragma unroll
        for (int j = 0; j < 8; ++j) acc[j] += b2f(a[j]);
    }
    {
        ushort8 a = *(const ushort8*)(gk + ((size_t)node << 6) + poff);
#pragma unroll
        for (int j = 0; j < 8; ++j) acc[j] += b2f(a[j]);
    }

    ushort8 xv = *(const ushort8*)(xb0 + ((size_t)node << 6) + poff);
    float res[8];
#pragma unroll
    for (int j = 0; j < 8; ++j) res[j] = 0.9f * di * acc[j] + b2f(xv[j]);

    if (LAST) {
        float4* o4 = (float4*)(out + (size_t)node * OUTF + poff);
        o4[0] = make_float4(res[0], res[1], res[2], res[3]);
        o4[1] = make_float4(res[4], res[5], res[6], res[7]);
    } else {
        ushort8 o;
#pragma unroll
        for (int j = 0; j < 8; ++j) o[j] = f2b(di * res[j]);
        *(ushort8*)(gn + ((size_t)node << 6) + poff) = o;
    }
}

extern "C" void kernel_launch(void* const* d_in, const int* in_sizes, int n_in,
                              void* d_out, int out_size, void* d_ws, size_t ws_size,
                              hipStream_t stream) {
    const float* x = (const float*)d_in[0];
    const void* ei = d_in[1];
    const float* w1 = (const float*)d_in[2];
    const float* b1 = (const float*)d_in[3];
    const float* w2 = (const float*)d_in[4];
    const float* b2 = (const float*)d_in[5];
    float* out = (float*)d_out;

    int n = in_sizes[0] / HIDDEN;              // 100000
    long long E = (long long)in_sizes[1] / 2;  // 3200000
    int nb = (n + 255) >> 8;                   // 391 buckets

    char* ws = (char*)d_ws;
    size_t off = 0;
    auto alloc = [&](size_t bytes) {
        void* p = ws + off;
        off += (bytes + 511) & ~(size_t)511;
        return p;
    };
    unsigned short* xb0 = (unsigned short*)alloc((size_t)n * OUTF * 2);  // 12.8 MB
    size_t gmark = off;
    unsigned short* gA = (unsigned short*)alloc((size_t)n * OUTF * 2);   // 12.8 MB
    unsigned short* gB = (unsigned short*)alloc((size_t)n * OUTF * 2);   // 12.8 MB
    unsigned int* pairs = (unsigned int*)(ws + gmark);  // 12.8 MB, aliases gA/gB (dead pre-MLP)
    float* dinv = (float*)alloc((size_t)n * 4);
    int* ofs = (int*)alloc((size_t)(n + 1) * 4);
    int* csr_src = (int*)alloc((size_t)E * 4);                           // 12.8 MB
    int* bh = (int*)alloc((size_t)512 * NB_BLK * 4);
    int* pre = (int*)alloc((size_t)512 * NB_BLK * 4);
    int* btot = (int*)alloc(512 * 4);
    int* bofs = (int*)alloc(513 * 4);
    unsigned short* w1p = (unsigned short*)alloc(65536 * 2);
    unsigned short* w2p = (unsigned short*)alloc(16384 * 2);

    part_hist_kernel<<<NB_BLK, 256, 0, stream>>>(ei, E, bh, n, nb, w1, w2, w1p, w2p);
    part_colscan_kernel<<<nb, NB_BLK, 0, stream>>>(bh, pre, btot);
    part_bscan_kernel<<<1, 512, 0, stream>>>(btot, bofs, nb);
    part_scatter_kernel<<<NB_BLK, 256, 0, stream>>>(ei, E, bofs, pre, pairs, n, nb);
    csr_bucket_kernel<<<nb, 256, 0, stream>>>(pairs, bofs, ofs, dinv, csr_src, n, nb);

    mlp_mfma_kernel<<<(n + 63) / 64, 512, 0, stream>>>(x, w1p, b1, w2p, b2, dinv, xb0, gA, n);

    int prop_blocks = (int)(((size_t)n * 8 + 255) / 256);
    for (int k = 0; k < 10; ++k) {
        const unsigned short* gin = (k & 1) ? gB : gA;
        unsigned short* gout = (k & 1) ? gA : gB;
        if (k == 9) {
            prop_kernel<1><<<prop_blocks, 256, 0, stream>>>(gin, xb0, nullptr, out, ofs,
                                                            csr_src, dinv, n);
        } else {
            prop_kernel<0><<<prop_blocks, 256, 0, stream>>>(gin, xb0, gout, nullptr, ofs,
                                                            csr_src, dinv, n);
        }
    }
}